// Round 3
// baseline (80.600 us; speedup 1.0000x reference)
//
#include <hip/hip_runtime.h>
#include <hip/hip_fp16.h>
#include <math.h>

#define N_GENES 20000
#define UNITS   10000
#define DEG     32
#define BATCH   128
#define UPB     16    // units per block (gather)

// Kernel 1: featT[g][b] = (half)|feature[b][g]| -- 32x32 LDS tile, fused abs+cvt.
__global__ __launch_bounds__(256) void transpose_abs_f16_kernel(
    const float* __restrict__ in, __half* __restrict__ out)
{
    __shared__ float tile[32][33];
    const int g0 = blockIdx.x * 32;
    const int b0 = blockIdx.y * 32;
    const int tx = threadIdx.x;   // 0..31
    const int ty = threadIdx.y;   // 0..7
#pragma unroll
    for (int i = 0; i < 32; i += 8)
        tile[ty + i][tx] = fabsf(in[(size_t)(b0 + ty + i) * N_GENES + (g0 + tx)]);
    __syncthreads();
#pragma unroll
    for (int i = 0; i < 32; i += 8)
        out[(size_t)(g0 + ty + i) * BATCH + (b0 + tx)] = __float2half(tile[tx][ty + i]);
}

// Kernel 2: 625 blocks x 256 threads; 16 units/block, 4 units/wave.
// Quarter-wave q handles d = it*4+q; lane's 16-B load covers batches 8c..8c+7.
// 8 dwordx4 loads per (wave,unit) instead of 32 dword loads.
__global__ __launch_bounds__(256) void gather_unit_kernel(
    const __half* __restrict__ featT,    // [N_GENES][BATCH] fp16
    const int*   __restrict__ ppi,
    const float* __restrict__ kernelw,
    const float* __restrict__ bias,
    float*       __restrict__ out)
{
    __shared__ int   idx[UPB * DEG];     // 2 KB
    __shared__ float res[UPB][BATCH];    // 8 KB

    const int tid = threadIdx.x;
    const int u0  = blockIdx.x * UPB;

    {
        const int* src = ppi + (size_t)u0 * DEG;
        idx[tid]       = src[tid];
        idx[tid + 256] = src[tid + 256];
    }
    __syncthreads();

    const int lane = tid & 63;
    const int w    = tid >> 6;           // wave 0..3
    const int q    = lane >> 4;          // quarter 0..3 -> d-offset
    const int c    = lane & 15;          // batch group: 8c..8c+7

#pragma unroll 2
    for (int uu = 0; uu < 4; ++uu) {
        const int ul = w * 4 + uu;       // local unit
        float acc[8] = {0.f,0.f,0.f,0.f,0.f,0.f,0.f,0.f};
#pragma unroll
        for (int it = 0; it < 8; ++it) {
            const int g = idx[ul * DEG + it * 4 + q];            // LDS broadcast x4
            const float4 raw = *(const float4*)(featT + (size_t)g * BATCH + c * 8);
            const __half2* h2 = (const __half2*)&raw;
#pragma unroll
            for (int p = 0; p < 4; ++p) {
                const float2 f = __half22float2(h2[p]);
                acc[2 * p]     += f.x;
                acc[2 * p + 1] += f.y;
            }
        }
        const int u   = u0 + ul;
        const float kk = kernelw[u];
        const float bb = bias[u];
        // combine the 4 quarter-wave partials (each covered 8 of 32 d's)
#pragma unroll
        for (int j = 0; j < 8; ++j) {
            float v = acc[j];
            v += __shfl_xor(v, 16, 64);
            v += __shfl_xor(v, 32, 64);
            acc[j] = v;
        }
        if (q == 0) {
#pragma unroll
            for (int j = 0; j < 8; ++j) {
                const float h = acc[j] * kk + bb;
                // tanh(h) = 1 - 2/(exp(2h)+1)
                res[ul][c * 8 + j] = 1.f - 2.f / (__expf(2.f * h) + 1.f);
            }
        }
    }
    __syncthreads();

    // write out[b][u0..u0+15]: 2 threads per batch row -> full 64-B lines
    const int b    = tid >> 1;           // 0..127
    const int half = tid & 1;            // unit sub-block of 8
    float v[8];
#pragma unroll
    for (int j = 0; j < 8; ++j) v[j] = res[half * 8 + j][b];
    float4* o = (float4*)(out + (size_t)b * UNITS + u0 + half * 8);
    o[0] = make_float4(v[0], v[1], v[2], v[3]);
    o[1] = make_float4(v[4], v[5], v[6], v[7]);
}

extern "C" void kernel_launch(void* const* d_in, const int* in_sizes, int n_in,
                              void* d_out, int out_size, void* d_ws, size_t ws_size,
                              hipStream_t stream) {
    const float* feature = (const float*)d_in[0];
    const int*   ppi     = (const int*)d_in[1];
    const float* kernelw = (const float*)d_in[2];
    const float* bias    = (const float*)d_in[3];
    float* out   = (float*)d_out;
    __half* featT = (__half*)d_ws;                 // 20000*128*2 = 5.12 MB

    dim3 g1(N_GENES / 32, BATCH / 32);
    dim3 b1(32, 8);
    transpose_abs_f16_kernel<<<g1, b1, 0, stream>>>(feature, featT);

    gather_unit_kernel<<<UNITS / UPB, 256, 0, stream>>>(
        featT, ppi, kernelw, bias, out);
}

// Round 4
// 80.053 us; speedup vs baseline: 1.0068x; 1.0068x over previous
//
#include <hip/hip_runtime.h>
#include <hip/hip_fp16.h>
#include <math.h>

#define N_GENES 20000
#define UNITS   10000
#define DEG     32
#define BATCH   128
#define UPB     16    // units per block (gather)

// Kernel 1: featT[p][g][b'] = (half)|feature[b][g]|, p = b>>6, b' = b&63.
// Two 2.56 MB batch-planes so each phase's working set fits a 4 MB per-XCD L2.
__global__ __launch_bounds__(256) void transpose_abs_f16_kernel(
    const float* __restrict__ in, __half* __restrict__ out)
{
    __shared__ float tile[32][33];
    const int g0 = blockIdx.x * 32;
    const int b0 = blockIdx.y * 32;
    const int tx = threadIdx.x;   // 0..31
    const int ty = threadIdx.y;   // 0..7
#pragma unroll
    for (int i = 0; i < 32; i += 8)
        tile[ty + i][tx] = fabsf(in[(size_t)(b0 + ty + i) * N_GENES + (g0 + tx)]);
    __syncthreads();
    const int b  = b0 + tx;
    const size_t plane = (size_t)(b >> 6) * N_GENES * 64;
    const int bp = b & 63;
#pragma unroll
    for (int i = 0; i < 32; i += 8)
        out[plane + (size_t)(g0 + ty + i) * 64 + bp] = __float2half(tile[tx][ty + i]);
}

// Kernel 2: 625 blocks x 4 waves; 16 units/block, 4 units/wave.
// Phase p processes batch-plane p (2.56 MB hot set device-wide).
// Lane: c = lane&31 -> batches 2c,2c+1 (half2); dh = lane>>5 -> d parity.
__global__ __launch_bounds__(256) void gather_unit_kernel(
    const __half* __restrict__ featT,    // [2][N_GENES][64] fp16
    const int*   __restrict__ ppi,
    const float* __restrict__ kernelw,
    const float* __restrict__ bias,
    float*       __restrict__ out)
{
    __shared__ int   idx[UPB * DEG];     // 2 KB
    __shared__ float res[UPB][BATCH];    // 8 KB

    const int tid = threadIdx.x;
    const int u0  = blockIdx.x * UPB;

    {
        const int* src = ppi + (size_t)u0 * DEG;
        idx[tid]       = src[tid];
        idx[tid + 256] = src[tid + 256];
    }
    __syncthreads();

    const int lane = tid & 63;
    const int w    = tid >> 6;           // wave 0..3
    const int c    = lane & 31;          // half2 index: batches 2c, 2c+1
    const int dh   = lane >> 5;          // 0/1: d parity

#pragma unroll
    for (int p = 0; p < 2; ++p) {
        const __half2* plane = (const __half2*)(featT + (size_t)p * N_GENES * 64);
#pragma unroll 2
        for (int uu = 0; uu < 4; ++uu) {
            const int ul = w * 4 + uu;   // local unit
            float2 acc = {0.f, 0.f};
#pragma unroll
            for (int it = 0; it < 16; ++it) {
                const int g = idx[ul * DEG + it * 2 + dh];        // LDS broadcast
                const float2 f = __half22float2(plane[(size_t)g * 32 + c]);
                acc.x += f.x; acc.y += f.y;
            }
            // combine d-parity halves (lane <-> lane^32)
            acc.x += __shfl_xor(acc.x, 32, 64);
            acc.y += __shfl_xor(acc.y, 32, 64);
            if (dh == 0) {
                const int u = u0 + ul;
                const float kk = kernelw[u];
                const float bb = bias[u];
                const float h0 = acc.x * kk + bb;
                const float h1 = acc.y * kk + bb;
                // tanh(h) = 1 - 2/(exp(2h)+1)
                res[ul][p * 64 + 2 * c]     = 1.f - 2.f / (__expf(2.f * h0) + 1.f);
                res[ul][p * 64 + 2 * c + 1] = 1.f - 2.f / (__expf(2.f * h1) + 1.f);
            }
        }
    }
    __syncthreads();

    // write out[b][u0..u0+15]: 2 threads per batch row -> full 64-B lines
    const int b    = tid >> 1;           // 0..127
    const int half = tid & 1;            // unit sub-block of 8
    float v[8];
#pragma unroll
    for (int j = 0; j < 8; ++j) v[j] = res[half * 8 + j][b];
    float4* o = (float4*)(out + (size_t)b * UNITS + u0 + half * 8);
    o[0] = make_float4(v[0], v[1], v[2], v[3]);
    o[1] = make_float4(v[4], v[5], v[6], v[7]);
}

extern "C" void kernel_launch(void* const* d_in, const int* in_sizes, int n_in,
                              void* d_out, int out_size, void* d_ws, size_t ws_size,
                              hipStream_t stream) {
    const float* feature = (const float*)d_in[0];
    const int*   ppi     = (const int*)d_in[1];
    const float* kernelw = (const float*)d_in[2];
    const float* bias    = (const float*)d_in[3];
    float* out   = (float*)d_out;
    __half* featT = (__half*)d_ws;                 // 2 planes x 2.56 MB

    dim3 g1(N_GENES / 32, BATCH / 32);
    dim3 b1(32, 8);
    transpose_abs_f16_kernel<<<g1, b1, 0, stream>>>(feature, featT);

    gather_unit_kernel<<<UNITS / UPB, 256, 0, stream>>>(
        featT, ppi, kernelw, bias, out);
}